// Round 5
// baseline (112.770 us; speedup 1.0000x reference)
//
#include <hip/hip_runtime.h>
#include <stdint.h>

// DEQ: z_{t+1} = tanh(c + z_t @ B_w^T), c = x@A_w^T + A_b + B_b (fp32, computed once).
// ||B_w||_2 ~= 0.115 -> contraction; 5 Picard applications converge to ~6e-6 in y.
//
// r0-r4 post-mortem: five structures, all 52-53us; no pipe saturated; r4 absorbed
// 86MB of spill traffic for free. Invariant = per-wave instruction stream
// (VALUBusy*dur ~= 22us every round). This round SHRINKS the stream:
//
// 32x32x16_f16 MFMA, one 32-state x 32-batch tile per wave (state-split kept):
//   A (B_w slice): lane holds B_w[32wv+(l&31)][16kt+8h+j], j=0..7 (half8), h=l>>5.
//   B (z^T):       lane holds zex[l&31][16kt+8h+j]          (two b64 reads).
//   C/D:           col=l&31, row=(reg&3)+8*(reg>>2)+4h  [m74/m101, dtype-indep]
//                  => reg=4g+r maps to state s=32wv+8g+4h+r; reg pairs r={0,1},{2,3}
//                  are ADJACENT states -> tanh+cvt_pkrtz pair packs to one b32 write.
//   8 MFMAs/app (was 32), LDS writes 8 b32 (was 8 b64), reads 16 b64 for 2x output.
//   ~25-30% fewer issued instructions/wave; regs ~110 (no spill at (256,4)).
// s_setprio(1) around the MFMA chain (T5): blocks at independent phases.
// Exchange structure from r3 verbatim: ZS=132 (zero measured conflicts), 17.4KB LDS.

typedef _Float16 half8  __attribute__((ext_vector_type(8)));
typedef _Float16 half4  __attribute__((ext_vector_type(4)));
typedef __fp16   fp16x2 __attribute__((ext_vector_type(2)));  // cvt_pkrtz native type
typedef float    f32x4  __attribute__((ext_vector_type(4)));
typedef float    f32x16 __attribute__((ext_vector_type(16)));

#define ZS 132   // f16 per z-row: 128 states + 4 pad (264B rows; 0 conflicts measured r3)

union H2U { fp16x2 h; uint32_t u; };
union H8U { half8 h; half4 q[2]; uint32_t u[4]; };

__device__ __forceinline__ float tanh_fast(float v) {
    // tanh(v) = 1 - 2/(e^{2v}+1); v_exp_f32 + v_rcp_f32 (~1 ulp each)
    float e2 = __builtin_amdgcn_exp2f(v * 2.8853900817779268f); // 2*log2(e)
    return 1.0f - 2.0f * __builtin_amdgcn_rcpf(e2 + 1.0f);
}

__global__ __launch_bounds__(256, 4)
void deq_solve_kernel(const float* __restrict__ xin,
                      const float* __restrict__ A_w,
                      const float* __restrict__ A_b,
                      const float* __restrict__ B_w,
                      const float* __restrict__ B_b,
                      const float* __restrict__ h_w,
                      const float* __restrict__ h_b,
                      float* __restrict__ out)
{
    __shared__ __align__(16) _Float16 zex[2][32 * ZS];  // ping-pong z, [batch 32][state]
    __shared__ float red[4][32];                        // cross-wave output reduction

    const int tid  = threadIdx.x;
    const int lane = tid & 63;
    const int wv   = tid >> 6;       // wave owns states [32*wv, 32*wv+32)
    const int h    = lane >> 5;      // lane half (k-group / row offset +4h)
    const int n    = lane & 31;      // batch column

    // ---- af[kt]: B_w[32wv+n][16kt+8h+j], j=0..7 (f32->f16 direct, L2-resident) ----
    half8 af[8];
    {
        const float* arow = B_w + (wv * 32 + n) * 128 + 8 * h;
        #pragma unroll
        for (int kt = 0; kt < 8; ++kt) {
            f32x4 v0 = *(const f32x4*)(arow + 16 * kt);
            f32x4 v1 = *(const f32x4*)(arow + 16 * kt + 4);
            H8U w;
            H2U a, b, c, d;
            a.h = __builtin_amdgcn_cvt_pkrtz(v0[0], v0[1]);
            b.h = __builtin_amdgcn_cvt_pkrtz(v0[2], v0[3]);
            c.h = __builtin_amdgcn_cvt_pkrtz(v1[0], v1[1]);
            d.h = __builtin_amdgcn_cvt_pkrtz(v1[2], v1[3]);
            w.u[0] = a.u; w.u[1] = b.u; w.u[2] = c.u; w.u[3] = d.u;
            af[kt] = w.h;
        }
    }

    // ---- cf in C/D layout: cf[4g+r] = c[s=32wv+8g+4h+r][b0+n] ----
    const int b0 = blockIdx.x * 32;
    const f32x4 xv = *(const f32x4*)(xin + 4 * (b0 + n));
    f32x16 cf;
    #pragma unroll
    for (int g = 0; g < 4; ++g) {
        const int sb = wv * 32 + 8 * g + 4 * h;
        f32x4 ab = *(const f32x4*)(A_b + sb);
        f32x4 bb = *(const f32x4*)(B_b + sb);
        #pragma unroll
        for (int r = 0; r < 4; ++r) {
            f32x4 aw = *(const f32x4*)(A_w + 4 * (sb + r));
            cf[4 * g + r] = ab[r] + bb[r]
                          + aw[0]*xv[0] + aw[1]*xv[1] + aw[2]*xv[2] + aw[3]*xv[3];
        }
    }

    // tanh + pack adjacent-state reg pairs + b32 write to zex[BUF]
#define EPILOGUE(ACC, BUF)                                                     \
    _Pragma("unroll")                                                          \
    for (int g = 0; g < 4; ++g)                                                \
        _Pragma("unroll")                                                      \
        for (int rp = 0; rp < 2; ++rp) {                                       \
            H2U pk;                                                            \
            pk.h = __builtin_amdgcn_cvt_pkrtz(tanh_fast((ACC)[4*g + 2*rp]),    \
                                              tanh_fast((ACC)[4*g + 2*rp+1])); \
            *(uint32_t*)(&zex[BUF][n * ZS + wv * 32 + 8 * g + 4 * h + 2 * rp]) = pk.u; \
        }

#define LOADBF(RBUF)                                                           \
    _Pragma("unroll")                                                          \
    for (int kt = 0; kt < 8; ++kt) {                                           \
        H8U t;                                                                 \
        t.q[0] = *(const half4*)(&zex[RBUF][n * ZS + 16 * kt + 8 * h]);        \
        t.q[1] = *(const half4*)(&zex[RBUF][n * ZS + 16 * kt + 8 * h + 4]);    \
        bf[kt] = t.h;                                                          \
    }

#define MFMA_CHAIN(ACC)                                                        \
    __builtin_amdgcn_s_setprio(1);                                             \
    (ACC) = __builtin_amdgcn_mfma_f32_32x32x16_f16(af[0], bf[0], cf, 0, 0, 0); \
    _Pragma("unroll")                                                          \
    for (int kt = 1; kt < 8; ++kt)                                             \
        (ACC) = __builtin_amdgcn_mfma_f32_32x32x16_f16(af[kt], bf[kt], (ACC), 0, 0, 0); \
    __builtin_amdgcn_s_setprio(0);

    half8 bf[8];

    // ---- application 1: z1 = tanh(c) ----
    EPILOGUE(cf, 0)
    __syncthreads();

    // ---- applications 2..4 (ping-pong; one barrier per app) ----
    {
        f32x16 acc;
        LOADBF(0) MFMA_CHAIN(acc) EPILOGUE(acc, 1) __syncthreads();
        LOADBF(1) MFMA_CHAIN(acc) EPILOGUE(acc, 0) __syncthreads();
        LOADBF(0) MFMA_CHAIN(acc) EPILOGUE(acc, 1) __syncthreads();
    }

    // ---- application 5 fused with output: y = h_w . tanh(acc) + h_b ----
    float partial = 0.f;
    {
        f32x16 acc;
        LOADBF(1)
        MFMA_CHAIN(acc)
        #pragma unroll
        for (int g = 0; g < 4; ++g) {
            f32x4 hw = *(const f32x4*)(h_w + wv * 32 + 8 * g + 4 * h);
            #pragma unroll
            for (int r = 0; r < 4; ++r)
                partial += tanh_fast(acc[4 * g + r]) * hw[r];
        }
    }
    // lane l and l+32 hold complementary 16-state halves of batch col n
    partial += __shfl_xor(partial, 32);
    if (lane < 32)
        red[wv][lane] = partial;
    __syncthreads();
    if (tid < 32)
        out[b0 + tid] = red[0][tid] + red[1][tid] + red[2][tid] + red[3][tid] + h_b[0];
}

extern "C" void kernel_launch(void* const* d_in, const int* in_sizes, int n_in,
                              void* d_out, int out_size, void* d_ws, size_t ws_size,
                              hipStream_t stream) {
    const float* x   = (const float*)d_in[0];
    const float* A_w = (const float*)d_in[1];
    const float* A_b = (const float*)d_in[2];
    const float* B_w = (const float*)d_in[3];
    const float* B_b = (const float*)d_in[4];
    const float* h_w = (const float*)d_in[5];
    const float* h_b = (const float*)d_in[6];
    float* outp = (float*)d_out;

    int batch = in_sizes[0] / 4;   // 131072
    int grid  = batch / 32;        // 32 batch per block (4 waves, state-split)
    deq_solve_kernel<<<grid, 256, 0, stream>>>(x, A_w, A_b, B_w, B_b, h_w, h_b, outp);
}

// Round 6
// 109.889 us; speedup vs baseline: 1.0262x; 1.0262x over previous
//
#include <hip/hip_runtime.h>
#include <stdint.h>

// DEQ: z_{t+1} = tanh(c + z_t @ B_w^T), c = x@A_w^T + A_b + B_b (fp32, computed once).
// ||B_w||_2 ~= 0.115 -> contraction; 5 Picard applications converge to ~6e-6 in y.
//
// 32x32x16_f16 MFMA, state-split (wave wv owns states [32wv,32wv+32)):
//   A (B_w slice): lane holds B_w[32wv+(l&31)][16kt+8h+j], j=0..7 (half8), h=l>>5.
//   B (z^T):       lane holds zex[batchrow][16kt+8h+j]      (two b64 reads).
//   C/D:           col=l&31, row=(reg&3)+8*(reg>>2)+4h  [m74/m101, dtype-indep]
//                  -> reg=4g+r is state s=32wv+8g+4h+r; r pairs pack to b32,
//                  rp pairs pack to one b64 LDS write.
//
// r6: DUAL-BATCH-TILE interleave. Each wave runs TWO independent 32-batch tiles:
//   - two MFMA chains interleaved kt-by-kt (acc0/acc1) -> each dependent MFMA's
//     latency is covered by the other chain's issue (r5 had ONE naked chain);
//   - setup (af cvt, cf build, A_w loads) amortized over 64 batch (2x);
//   - single z buffer + {read-barrier, write-barrier} per app instead of
//     ping-pong (LDS 17.5KB -> 4 blocks/CU preserved).
// Pre-commitment: 7th structure; if still 50-56us -> external floor, ROOFLINE.

typedef _Float16 half8  __attribute__((ext_vector_type(8)));
typedef _Float16 half4  __attribute__((ext_vector_type(4)));
typedef __fp16   fp16x2 __attribute__((ext_vector_type(2)));  // cvt_pkrtz native type
typedef float    f32x4  __attribute__((ext_vector_type(4)));
typedef float    f32x16 __attribute__((ext_vector_type(16)));
typedef uint32_t u32x2  __attribute__((ext_vector_type(2)));

#define ZS 132   // f16 per z-row: 128 states + 4 pad; 264B rows -> 2-way alias (free, 0 conflicts r3/r5)

union H2U { fp16x2 h; uint32_t u; };
union H8U { half8 h; half4 q[2]; uint32_t u[4]; };

__device__ __forceinline__ float tanh_fast(float v) {
    // tanh(v) = 1 - 2/(e^{2v}+1); v_exp_f32 + v_rcp_f32 (~1 ulp each)
    float e2 = __builtin_amdgcn_exp2f(v * 2.8853900817779268f); // 2*log2(e)
    return 1.0f - 2.0f * __builtin_amdgcn_rcpf(e2 + 1.0f);
}

__global__ __launch_bounds__(256, 4)
void deq_solve_kernel(const float* __restrict__ xin,
                      const float* __restrict__ A_w,
                      const float* __restrict__ A_b,
                      const float* __restrict__ B_w,
                      const float* __restrict__ B_b,
                      const float* __restrict__ h_w,
                      const float* __restrict__ h_b,
                      float* __restrict__ out)
{
    __shared__ __align__(16) _Float16 zex[64 * ZS];   // single z buffer, [batch 64][state]
    __shared__ float red[4][64];                      // cross-wave output reduction

    const int tid  = threadIdx.x;
    const int lane = tid & 63;
    const int wv   = tid >> 6;       // wave owns states [32*wv, 32*wv+32)
    const int h    = lane >> 5;      // lane half (k-group / row offset +4h)
    const int n    = lane & 31;      // batch column within tile

    // ---- af[kt]: B_w[32wv+n][16kt+8h+j], j=0..7 (f32->f16 direct, L2-resident) ----
    half8 af[8];
    {
        const float* arow = B_w + (wv * 32 + n) * 128 + 8 * h;
        #pragma unroll
        for (int kt = 0; kt < 8; ++kt) {
            f32x4 v0 = *(const f32x4*)(arow + 16 * kt);
            f32x4 v1 = *(const f32x4*)(arow + 16 * kt + 4);
            H8U w; H2U a, b, c, d;
            a.h = __builtin_amdgcn_cvt_pkrtz(v0[0], v0[1]);
            b.h = __builtin_amdgcn_cvt_pkrtz(v0[2], v0[3]);
            c.h = __builtin_amdgcn_cvt_pkrtz(v1[0], v1[1]);
            d.h = __builtin_amdgcn_cvt_pkrtz(v1[2], v1[3]);
            w.u[0] = a.u; w.u[1] = b.u; w.u[2] = c.u; w.u[3] = d.u;
            af[kt] = w.h;
        }
    }

    // ---- cf0/cf1 in C/D layout: cf_t[4g+r] = c[s=32wv+8g+4h+r][b0+32t+n] ----
    const int b0 = blockIdx.x * 64;
    const f32x4 xv0 = *(const f32x4*)(xin + 4 * (b0 + n));
    const f32x4 xv1 = *(const f32x4*)(xin + 4 * (b0 + 32 + n));
    f32x16 cf0, cf1;
    #pragma unroll
    for (int g = 0; g < 4; ++g) {
        const int sb = wv * 32 + 8 * g + 4 * h;
        f32x4 ab = *(const f32x4*)(A_b + sb);
        f32x4 bb = *(const f32x4*)(B_b + sb);
        #pragma unroll
        for (int r = 0; r < 4; ++r) {
            f32x4 aw = *(const f32x4*)(A_w + 4 * (sb + r));
            float base = ab[r] + bb[r];
            cf0[4 * g + r] = base + aw[0]*xv0[0] + aw[1]*xv0[1] + aw[2]*xv0[2] + aw[3]*xv0[3];
            cf1[4 * g + r] = base + aw[0]*xv1[0] + aw[1]*xv1[1] + aw[2]*xv1[2] + aw[3]*xv1[3];
        }
    }

    // tanh + pack rp-pairs + single b64 write per g, tile T batch row = 32T+n
#define EPILOGUE_T(ACC, T)                                                     \
    _Pragma("unroll")                                                          \
    for (int g = 0; g < 4; ++g) {                                              \
        H2U pa, pb;                                                            \
        pa.h = __builtin_amdgcn_cvt_pkrtz(tanh_fast((ACC)[4*g + 0]),           \
                                          tanh_fast((ACC)[4*g + 1]));          \
        pb.h = __builtin_amdgcn_cvt_pkrtz(tanh_fast((ACC)[4*g + 2]),           \
                                          tanh_fast((ACC)[4*g + 3]));          \
        u32x2 w = { pa.u, pb.u };                                              \
        *(u32x2*)(&zex[((T) * 32 + n) * ZS + wv * 32 + 8 * g + 4 * h]) = w;    \
    }

    // dual interleaved MFMA chains over zex (reads on-demand, 2 b64 per tile per kt)
#define APP_CHAIN(A0, A1)                                                      \
    __builtin_amdgcn_s_setprio(1);                                             \
    {                                                                          \
        H8U t0, t1;                                                            \
        t0.q[0] = *(const half4*)(&zex[n * ZS + 8 * h]);                       \
        t0.q[1] = *(const half4*)(&zex[n * ZS + 8 * h + 4]);                   \
        t1.q[0] = *(const half4*)(&zex[(32 + n) * ZS + 8 * h]);                \
        t1.q[1] = *(const half4*)(&zex[(32 + n) * ZS + 8 * h + 4]);            \
        (A0) = __builtin_amdgcn_mfma_f32_32x32x16_f16(af[0], t0.h, cf0, 0, 0, 0); \
        (A1) = __builtin_amdgcn_mfma_f32_32x32x16_f16(af[0], t1.h, cf1, 0, 0, 0); \
    }                                                                          \
    _Pragma("unroll")                                                          \
    for (int kt = 1; kt < 8; ++kt) {                                           \
        H8U t0, t1;                                                            \
        t0.q[0] = *(const half4*)(&zex[n * ZS + 16 * kt + 8 * h]);             \
        t0.q[1] = *(const half4*)(&zex[n * ZS + 16 * kt + 8 * h + 4]);         \
        t1.q[0] = *(const half4*)(&zex[(32 + n) * ZS + 16 * kt + 8 * h]);      \
        t1.q[1] = *(const half4*)(&zex[(32 + n) * ZS + 16 * kt + 8 * h + 4]);  \
        (A0) = __builtin_amdgcn_mfma_f32_32x32x16_f16(af[kt], t0.h, (A0), 0, 0, 0); \
        (A1) = __builtin_amdgcn_mfma_f32_32x32x16_f16(af[kt], t1.h, (A1), 0, 0, 0); \
    }                                                                          \
    __builtin_amdgcn_s_setprio(0);

    // ---- application 1: z1 = tanh(c) ----
    EPILOGUE_T(cf0, 0)
    EPILOGUE_T(cf1, 1)
    __syncthreads();

    // ---- applications 2..4: read z_k -> barrier -> write z_{k+1} -> barrier ----
    #pragma unroll 1
    for (int it = 0; it < 3; ++it) {
        f32x16 a0, a1;
        APP_CHAIN(a0, a1)
        __syncthreads();          // all waves done reading z_k
        EPILOGUE_T(a0, 0)
        EPILOGUE_T(a1, 1)
        __syncthreads();          // z_{k+1} visible to all waves
    }

    // ---- application 5 fused with output: y = h_w . tanh(acc) + h_b ----
    float p0 = 0.f, p1 = 0.f;
    {
        f32x16 a0, a1;
        APP_CHAIN(a0, a1)         // last read of zex; no barrier needed after
        #pragma unroll
        for (int g = 0; g < 4; ++g) {
            f32x4 hw = *(const f32x4*)(h_w + wv * 32 + 8 * g + 4 * h);
            #pragma unroll
            for (int r = 0; r < 4; ++r) {
                p0 += tanh_fast(a0[4 * g + r]) * hw[r];
                p1 += tanh_fast(a1[4 * g + r]) * hw[r];
            }
        }
    }
    // lanes l and l^32 hold complementary 16-state halves of the same batch col
    p0 += __shfl_xor(p0, 32);
    p1 += __shfl_xor(p1, 32);
    // h=0 lanes store tile0 at [n], h=1 lanes store tile1 at [32+n]
    red[wv][h ? (32 + n) : n] = h ? p1 : p0;
    __syncthreads();
    if (tid < 64)
        out[b0 + tid] = red[0][tid] + red[1][tid] + red[2][tid] + red[3][tid] + h_b[0];
}

extern "C" void kernel_launch(void* const* d_in, const int* in_sizes, int n_in,
                              void* d_out, int out_size, void* d_ws, size_t ws_size,
                              hipStream_t stream) {
    const float* x   = (const float*)d_in[0];
    const float* A_w = (const float*)d_in[1];
    const float* A_b = (const float*)d_in[2];
    const float* B_w = (const float*)d_in[3];
    const float* B_b = (const float*)d_in[4];
    const float* h_w = (const float*)d_in[5];
    const float* h_b = (const float*)d_in[6];
    float* outp = (float*)d_out;

    int batch = in_sizes[0] / 4;   // 131072
    int grid  = batch / 64;        // 64 batch per block (4 waves, state-split, dual tile)
    deq_solve_kernel<<<grid, 256, 0, stream>>>(x, A_w, A_b, B_w, B_b, h_w, h_b, outp);
}

// Round 7
// 104.759 us; speedup vs baseline: 1.0765x; 1.0490x over previous
//
#include <hip/hip_runtime.h>
#include <stdint.h>

// DEQ: z_{t+1} = tanh(c + z_t @ B_w^T), c = x@A_w^T + A_b + B_b (fp32, computed once).
// ||B_w||_2 ~= 0.115 -> contraction; 5 Picard applications converge to ~6e-6 in y.
//
// FINAL KERNEL = round-3 state-split structure, restored verbatim (best measured:
// rocprof 52.0us, bench 105.2us, VGPR 52, 0 bank conflicts, 0 spill).
//
// Transposed MFMA 16x16x16_f16: z^T[s][b] = sum_k B_w[s][k] z^T[k][b].
//   Layout identity (r1, verified): B-operand layout (k=quad*4+j, n=lane&15) ==
//   C/D layout (row=quad*4+r, col=lane&15), so tanh(acc)+cvt_pkrtz written
//   state-contiguous IS the next B-fragment (b64 read).
//   Wave wv owns states [32wv,32wv+32) x 32 batch; af = 32 regs direct from
//   global (L2-resident); z exchanged via tiny ping-pong LDS buffer
//   (4 b64 writes + 16 b64 reads per wave per app, 1 barrier per app).
//
// Session conclusion (r0-r6): seven structurally distinct kernels (occupancy
// 18-35%, barriers 0-20, LDS traffic 30x range, MFMA count 4x range, up to
// 86MB gratuitous spill traffic) ALL land at 52-56us rocprof. No pipe exceeds
// ~47%; all per-pipe arithmetic floors are <20us. The 52us floor is time-based
// and external to per-wave code (DVFS ramp / dispatch-scale floor: timed
// dispatches are 1-5ms apart, starting from idled clocks). Further kernel-source
// optimization is not expected to move the bench number.

typedef _Float16 half4  __attribute__((ext_vector_type(4)));
typedef __fp16   fp16x2 __attribute__((ext_vector_type(2)));  // cvt_pkrtz native type
typedef float    f32x4  __attribute__((ext_vector_type(4)));

#define ZS 132   // f16 per z-exchange row: [batch 32][state 128 + 4 pad] (264B rows, 8B aligned)

union H2U { fp16x2 h; uint32_t u; };
union H4U { half4 h; uint32_t u[2]; };

__device__ __forceinline__ float tanh_fast(float v) {
    // tanh(v) = 1 - 2/(e^{2v}+1); v_exp_f32 + v_rcp_f32 (~1 ulp each)
    float e2 = __builtin_amdgcn_exp2f(v * 2.8853900817779268f); // 2*log2(e)
    return 1.0f - 2.0f * __builtin_amdgcn_rcpf(e2 + 1.0f);
}

__global__ __launch_bounds__(256, 4)
void deq_solve_kernel(const float* __restrict__ xin,
                      const float* __restrict__ A_w,
                      const float* __restrict__ A_b,
                      const float* __restrict__ B_w,
                      const float* __restrict__ B_b,
                      const float* __restrict__ h_w,
                      const float* __restrict__ h_b,
                      float* __restrict__ out)
{
    __shared__ __align__(16) _Float16 zex[2][32 * ZS];  // ping-pong z, [batch][state]
    __shared__ float red[4][32];                        // cross-wave output reduction

    const int tid  = threadIdx.x;
    const int lane = tid & 63;
    const int wv   = tid >> 6;       // wave owns states [32*wv, 32*wv+32)
    const int quad = lane >> 4;
    const int bcol = lane & 15;

    // ---- af(mt,kt): B_w[32wv+16mt+bcol][16kt+4quad+j], f32->f16 direct from
    //      global (64KB total, L2/L3-resident; no LDS staging). 32 VGPRs.
    half4 af[2][8];
    #pragma unroll
    for (int mt = 0; mt < 2; ++mt) {
        const f32x4* rowp = (const f32x4*)(B_w + (wv * 32 + mt * 16 + bcol) * 128 + quad * 4);
        #pragma unroll
        for (int kt = 0; kt < 8; ++kt) {
            f32x4 v = rowp[kt * 4];
            H2U a, b; H4U w;
            a.h = __builtin_amdgcn_cvt_pkrtz(v[0], v[1]);
            b.h = __builtin_amdgcn_cvt_pkrtz(v[2], v[3]);
            w.u[0] = a.u; w.u[1] = b.u;
            af[mt][kt] = w.h;
        }
    }

    // ---- cf(mt,nt): c for state s = 32wv+16mt+4quad+r, batch b0+16nt+bcol ----
    const int b0 = blockIdx.x * 32;
    f32x4 xv[2];
    #pragma unroll
    for (int nt = 0; nt < 2; ++nt)
        xv[nt] = *(const f32x4*)(xin + 4 * (b0 + nt * 16 + bcol));
    f32x4 cf[2][2];
    #pragma unroll
    for (int mt = 0; mt < 2; ++mt) {
        #pragma unroll
        for (int r = 0; r < 4; ++r) {
            int s = wv * 32 + mt * 16 + quad * 4 + r;
            f32x4 aw = *(const f32x4*)(A_w + 4 * s);
            float bias = A_b[s] + B_b[s];
            #pragma unroll
            for (int nt = 0; nt < 2; ++nt)
                cf[mt][nt][r] = bias + aw[0]*xv[nt][0] + aw[1]*xv[nt][1]
                                     + aw[2]*xv[nt][2] + aw[3]*xv[nt][3];
        }
    }

    half4 bf[8][2];   // B-fragments: full 128 states x 2 batch tiles

    // tanh + pack + write own state-slice to zex[BUF] (state-contiguous b64)
#define EPILOGUE(ACC, BUF)                                                     \
    _Pragma("unroll")                                                          \
    for (int mt = 0; mt < 2; ++mt)                                             \
        _Pragma("unroll")                                                      \
        for (int nt = 0; nt < 2; ++nt) {                                       \
            H2U pa, pb; H4U w;                                                 \
            pa.h = __builtin_amdgcn_cvt_pkrtz(tanh_fast((ACC)[mt][nt][0]),     \
                                              tanh_fast((ACC)[mt][nt][1]));    \
            pb.h = __builtin_amdgcn_cvt_pkrtz(tanh_fast((ACC)[mt][nt][2]),     \
                                              tanh_fast((ACC)[mt][nt][3]));    \
            w.u[0] = pa.u; w.u[1] = pb.u;                                      \
            *(half4*)(&zex[BUF][(nt * 16 + bcol) * ZS + wv * 32 + mt * 16 + quad * 4]) = w.h; \
        }

#define LOADBF(BUF)                                                            \
    _Pragma("unroll")                                                          \
    for (int kt = 0; kt < 8; ++kt)                                             \
        _Pragma("unroll")                                                      \
        for (int nt = 0; nt < 2; ++nt)                                         \
            bf[kt][nt] = *(const half4*)(&zex[BUF][(nt * 16 + bcol) * ZS + kt * 16 + quad * 4]);

#define MFMA_CHAIN(ACC)                                                        \
    _Pragma("unroll")                                                          \
    for (int mt = 0; mt < 2; ++mt)                                             \
        _Pragma("unroll")                                                      \
        for (int nt = 0; nt < 2; ++nt)                                         \
            (ACC)[mt][nt] = __builtin_amdgcn_mfma_f32_16x16x16f16(af[mt][0], bf[0][nt], cf[mt][nt], 0, 0, 0); \
    _Pragma("unroll")                                                          \
    for (int kt = 1; kt < 8; ++kt)                                             \
        _Pragma("unroll")                                                      \
        for (int mt = 0; mt < 2; ++mt)                                         \
            _Pragma("unroll")                                                  \
            for (int nt = 0; nt < 2; ++nt)                                     \
                (ACC)[mt][nt] = __builtin_amdgcn_mfma_f32_16x16x16f16(af[mt][kt], bf[kt][nt], (ACC)[mt][nt], 0, 0, 0);

    // ---- application 1: z1 = tanh(c) ----
    EPILOGUE(cf, 0)
    __syncthreads();

    // ---- applications 2..4 (ping-pong; one barrier per app) ----
    {
        f32x4 acc[2][2];
        LOADBF(0) MFMA_CHAIN(acc) EPILOGUE(acc, 1) __syncthreads();
        LOADBF(1) MFMA_CHAIN(acc) EPILOGUE(acc, 0) __syncthreads();
        LOADBF(0) MFMA_CHAIN(acc) EPILOGUE(acc, 1) __syncthreads();
    }

    // ---- application 5 fused with output: y = h_w . tanh(acc) + h_b ----
    float part0 = 0.f, part1 = 0.f;
    {
        f32x4 acc[2][2];
        LOADBF(1)
        MFMA_CHAIN(acc)
        #pragma unroll
        for (int mt = 0; mt < 2; ++mt) {
            f32x4 hw = *(const f32x4*)(h_w + wv * 32 + mt * 16 + quad * 4);
            #pragma unroll
            for (int r = 0; r < 4; ++r) {
                part0 += tanh_fast(acc[mt][0][r]) * hw[r];
                part1 += tanh_fast(acc[mt][1][r]) * hw[r];
            }
        }
    }
    // reduce over the 4 quads (butterfly) -> every lane holds full wave-partials
    part0 += __shfl_xor(part0, 16); part0 += __shfl_xor(part0, 32);
    part1 += __shfl_xor(part1, 16); part1 += __shfl_xor(part1, 32);
    if (lane < 32)
        red[wv][lane] = (lane < 16) ? part0 : part1;
    __syncthreads();
    if (tid < 32)
        out[b0 + tid] = red[0][tid] + red[1][tid] + red[2][tid] + red[3][tid] + h_b[0];
}

extern "C" void kernel_launch(void* const* d_in, const int* in_sizes, int n_in,
                              void* d_out, int out_size, void* d_ws, size_t ws_size,
                              hipStream_t stream) {
    const float* x   = (const float*)d_in[0];
    const float* A_w = (const float*)d_in[1];
    const float* A_b = (const float*)d_in[2];
    const float* B_w = (const float*)d_in[3];
    const float* B_b = (const float*)d_in[4];
    const float* h_w = (const float*)d_in[5];
    const float* h_b = (const float*)d_in[6];
    float* outp = (float*)d_out;

    int batch = in_sizes[0] / 4;   // 131072
    int grid  = batch / 32;        // 32 batch per block (4 waves, state-split)
    deq_solve_kernel<<<grid, 256, 0, stream>>>(x, A_w, A_b, B_w, B_b, h_w, h_b, outp);
}